// Round 7
// baseline (792.912 us; speedup 1.0000x reference)
//
#include <hip/hip_runtime.h>
#include <hip/hip_bf16.h>

// Vanilla tanh RNN. B=64, T=2048, I=64, H=128, fp32.
//   xw[b,t,h] = sum_i x[b,t,i]*W[h,i] + b_ih[h] + b_hh[h]
//   h_t = tanh(xw_t + h_{t-1} @ U^T);  outputs: ys [B,T,H], h_last [B,H]
//
// R7: R6's compile error proved gfx950 VALU cannot source AGPRs => R5's
// VGPR_Count=36 means the compiler parked u[] in AGPRs and paid a
// v_accvgpr_read per MAC (the observed 2x VALU issue). Fix: every MAC is
// inline-asm v_fma_f32 with "v" constraints on all operands — u must live
// in arch VGPRs at each use; at ~80 regs total pressure (cap 256/wave at
// 2 waves/SIMD) the allocator keeps them resident. Scan structure = R5
// (661us): 512 thr, quad k-split, skewed hbuf, 32-step LDS chunk staging.
// GEMM = R6 register-blocked 4x8 tile (R5 gemm was ~110us of 770).

#define RNN_B 64
#define RNN_T 2048
#define RNN_I 64
#define RNN_H 128
#define CH    32            // timesteps per staged chunk
#define NCH   (RNN_T / CH)  // 64 chunks

__device__ __forceinline__ float fast_tanh(float x) {
  // tanh(x) = 1 - 2/(e^{2x}+1);  e^{2x} = exp2(x * 2*log2(e))
  float e = __builtin_amdgcn_exp2f(x * 2.885390081777927f);
  return 1.0f - 2.0f * __builtin_amdgcn_rcpf(e + 1.0f);
}

template <int CTRL>
__device__ __forceinline__ float dpp_add(float s) {
  int o = __builtin_amdgcn_mov_dpp(__float_as_int(s), CTRL, 0xF, 0xF, true);
  return s + __int_as_float(o);
}

// fma with all operands forced into arch VGPRs (defeats AGPR offload)
#define FMA_V(acc, uu, hh) \
  asm("v_fma_f32 %0, %1, %2, %0" : "+v"(acc) : "v"(uu), "v"(hh))

// ---------------------------------------------------------------------------
// Kernel 1: xw = x @ W^T + (b_ih + b_hh).  M=B*T=131072, N=128, K=64.
// 2048 blocks x 256 threads; 64-row x 128-col tile per block.
// Register-blocked 4x8 micro-tile; x and W staged in LDS with stride 68
// (272 B) to break power-of-2 bank aliasing.
// ---------------------------------------------------------------------------
__global__ __launch_bounds__(256) void rnn_xw_gemm(
    const float* __restrict__ x, const float* __restrict__ W,
    const float* __restrict__ b_ih, const float* __restrict__ b_hh,
    float* __restrict__ xw) {
  const int tid = threadIdx.x;
  const int tr  = tid >> 4;   // 0..15  (row lane)
  const int tc  = tid & 15;   // 0..15  (col lane)

  __shared__ __align__(16) float xs[64 * 68];    // 17.0 KB
  __shared__ __align__(16) float ws[128 * 68];   // 34.8 KB

  const long rbase = (long)blockIdx.x * 64;

  // Stage x tile: 64 rows x 64 k = 1024 float4, 4 per thread.
  {
    const float4* xg = (const float4*)(x + rbase * RNN_I);
#pragma unroll
    for (int j = 0; j < 4; ++j) {
      int idx = tid + 256 * j;          // 0..1023
      int r = idx >> 4, k4 = idx & 15;
      *(float4*)(&xs[r * 68 + k4 * 4]) = xg[idx];
    }
  }
  // Stage W: 128 rows x 64 k = 2048 float4, 8 per thread.
  {
    const float4* wg = (const float4*)W;
#pragma unroll
    for (int j = 0; j < 8; ++j) {
      int idx = tid + 256 * j;          // 0..2047
      int c = idx >> 4, k4 = idx & 15;
      *(float4*)(&ws[c * 68 + k4 * 4]) = wg[idx];
    }
  }
  // Bias for this thread's 8 columns (col = tc + 16*cc).
  float bias[8];
#pragma unroll
  for (int cc = 0; cc < 8; ++cc)
    bias[cc] = b_ih[tc + 16 * cc] + b_hh[tc + 16 * cc];
  __syncthreads();

  float acc[4][8];
#pragma unroll
  for (int rr = 0; rr < 4; ++rr)
#pragma unroll
    for (int cc = 0; cc < 8; ++cc) acc[rr][cc] = 0.f;

  for (int kc = 0; kc < 16; ++kc) {
    float4 xv[4], wv[8];
#pragma unroll
    for (int rr = 0; rr < 4; ++rr)
      xv[rr] = *(const float4*)(&xs[(tr + 16 * rr) * 68 + kc * 4]);
#pragma unroll
    for (int cc = 0; cc < 8; ++cc)
      wv[cc] = *(const float4*)(&ws[(tc + 16 * cc) * 68 + kc * 4]);
#pragma unroll
    for (int rr = 0; rr < 4; ++rr)
#pragma unroll
      for (int cc = 0; cc < 8; ++cc) {
        acc[rr][cc] = fmaf(xv[rr].x, wv[cc].x, acc[rr][cc]);
        acc[rr][cc] = fmaf(xv[rr].y, wv[cc].y, acc[rr][cc]);
        acc[rr][cc] = fmaf(xv[rr].z, wv[cc].z, acc[rr][cc]);
        acc[rr][cc] = fmaf(xv[rr].w, wv[cc].w, acc[rr][cc]);
      }
  }

#pragma unroll
  for (int rr = 0; rr < 4; ++rr) {
    long row = rbase + tr + 16 * rr;
#pragma unroll
    for (int cc = 0; cc < 8; ++cc)
      xw[row * RNN_H + tc + 16 * cc] = acc[rr][cc] + bias[cc];
  }
}

// ---------------------------------------------------------------------------
// Kernel 2: sequential scan. 1 block/batch, 512 threads (8 waves, 2/SIMD).
// thread -> (h = tid>>2, q = tid&3): 32 U floats in regs (8 float4);
// quad-reduce: DPP quad_perm xor1 (0xB1) + xor2 (0x4E).
// h state double-buffered in LDS with quarter-skew layout:
//   h[k] lives at float offset (k>>5)*36 + (k&31)   (bank-disjoint quads)
// xw/out chunk-staged in LDS (32 steps) -> no global ops inside steps.
// All MACs via FMA_V (arch-VGPR-forced v_fma_f32).
// ---------------------------------------------------------------------------
__global__ __launch_bounds__(512, 2) void rnn_scan(
    const float* xw,            // aliases `out` — no __restrict__
    float* out, float* __restrict__ hlast,
    const float* __restrict__ h0, const float* __restrict__ U) {
  const int b   = blockIdx.x;
  const int tid = threadIdx.x;  // 0..511
  const int h   = tid >> 2;     // 0..127
  const int q   = tid & 3;      // k-quarter

  __shared__ __align__(16) float hbuf[2][4 * 36];    // 144 floats/buffer
  __shared__ __align__(16) float xbuf[CH * RNN_H];   // 16 KB
  __shared__ __align__(16) float obuf[CH * RNN_H];   // 16 KB

  // U[h][q*32 .. q*32+31] -> 8 float4 (32 VGPRs)
  const float4* U4 = (const float4*)(U + h * RNN_H + q * 32);
  float4 u[8];
#pragma unroll
  for (int j = 0; j < 8; ++j) u[j] = U4[j];

  if (tid < RNN_H) hbuf[0][(tid >> 5) * 36 + (tid & 31)] = h0[b * RNN_H + tid];

  const long base    = (long)b * RNN_T * RNN_H;
  const float4* xw4  = (const float4*)(xw + base);
  float4* out4       = (float4*)(out + base);
  float4* xb4        = (float4*)xbuf;
  const float4* ob4  = (const float4*)obuf;

  int cur = 0;
  for (int c = 0; c < NCH; ++c) {
    // Phase A: stage xw chunk c (1024 float4, 2/thread); flush out chunk c-1.
    float4 xr0 = xw4[(long)c * 1024 + tid];
    float4 xr1 = xw4[(long)c * 1024 + tid + 512];
    if (c > 0) {
      float4 o0 = ob4[tid];
      float4 o1 = ob4[tid + 512];
      out4[(long)(c - 1) * 1024 + tid]       = o0;
      out4[(long)(c - 1) * 1024 + tid + 512] = o1;
    }
    xb4[tid]       = xr0;
    xb4[tid + 512] = xr1;
    __syncthreads();

    // Phase B: 32 steps, LDS-only traffic
    for (int tc = 0; tc < CH; ++tc) {
      const float4* hp = (const float4*)(hbuf[cur] + q * 36);
      float4 h0v = hp[0], h1v = hp[1], h2v = hp[2], h3v = hp[3];
      float4 h4v = hp[4], h5v = hp[5], h6v = hp[6], h7v = hp[7];

      // 32 MACs: 4 independent chains of depth 8 (dep latency hidden)
      float a0 = 0.f, a1 = 0.f, a2 = 0.f, a3 = 0.f;
      FMA_V(a0, u[0].x, h0v.x); FMA_V(a1, u[0].y, h0v.y);
      FMA_V(a2, u[0].z, h0v.z); FMA_V(a3, u[0].w, h0v.w);
      FMA_V(a0, u[1].x, h1v.x); FMA_V(a1, u[1].y, h1v.y);
      FMA_V(a2, u[1].z, h1v.z); FMA_V(a3, u[1].w, h1v.w);
      FMA_V(a0, u[2].x, h2v.x); FMA_V(a1, u[2].y, h2v.y);
      FMA_V(a2, u[2].z, h2v.z); FMA_V(a3, u[2].w, h2v.w);
      FMA_V(a0, u[3].x, h3v.x); FMA_V(a1, u[3].y, h3v.y);
      FMA_V(a2, u[3].z, h3v.z); FMA_V(a3, u[3].w, h3v.w);
      FMA_V(a0, u[4].x, h4v.x); FMA_V(a1, u[4].y, h4v.y);
      FMA_V(a2, u[4].z, h4v.z); FMA_V(a3, u[4].w, h4v.w);
      FMA_V(a0, u[5].x, h5v.x); FMA_V(a1, u[5].y, h5v.y);
      FMA_V(a2, u[5].z, h5v.z); FMA_V(a3, u[5].w, h5v.w);
      FMA_V(a0, u[6].x, h6v.x); FMA_V(a1, u[6].y, h6v.y);
      FMA_V(a2, u[6].z, h6v.z); FMA_V(a3, u[6].w, h6v.w);
      FMA_V(a0, u[7].x, h7v.x); FMA_V(a1, u[7].y, h7v.y);
      FMA_V(a2, u[7].z, h7v.z); FMA_V(a3, u[7].w, h7v.w);

      float s = (a0 + a1) + (a2 + a3);
      s = dpp_add<0xB1>(s);  // + lane^1
      s = dpp_add<0x4E>(s);  // + lane^2: all 4 quad lanes hold full dot
      float val = fast_tanh(s + xbuf[tc * RNN_H + h]);
      if (q == 0) hbuf[cur ^ 1][(h >> 5) * 36 + (h & 31)] = val;  // next state
      if (q == 1) obuf[tc * RNN_H + h] = val;                     // output
      cur ^= 1;
      __syncthreads();
    }
  }

  // Final chunk flush + h_last (last step's barrier makes data visible)
  out4[(long)(NCH - 1) * 1024 + tid]       = ob4[tid];
  out4[(long)(NCH - 1) * 1024 + tid + 512] = ob4[tid + 512];
  if (tid < RNN_H)
    hlast[b * RNN_H + tid] = hbuf[cur][(tid >> 5) * 36 + (tid & 31)];
}

extern "C" void kernel_launch(void* const* d_in, const int* in_sizes, int n_in,
                              void* d_out, int out_size, void* d_ws, size_t ws_size,
                              hipStream_t stream) {
  const float* x    = (const float*)d_in[0];
  const float* h0   = (const float*)d_in[1];
  const float* W    = (const float*)d_in[2];
  const float* U    = (const float*)d_in[3];
  const float* b_ih = (const float*)d_in[4];
  const float* b_hh = (const float*)d_in[5];

  float* out   = (float*)d_out;                           // [B,T,H]
  float* hlast = out + (long)RNN_B * RNN_T * RNN_H;       // [B,H]

  // Stage 1: xw into the output region (read-before-write in scan, per chunk)
  rnn_xw_gemm<<<(RNN_B * RNN_T) / 64, 256, 0, stream>>>(x, W, b_ih, b_hh, out);
  // Stage 2: sequential recurrence, one block per batch element
  rnn_scan<<<RNN_B, 512, 0, stream>>>(out, out, hlast, h0, U);
}